// Round 12
// baseline (424.564 us; speedup 1.0000x reference)
//
#include <hip/hip_runtime.h>
#include <hip/hip_bf16.h>

#define B_ROWS 65536
#define NA 128
#define D_OUT 1024
#define VBS 128
#define NCHUNK (B_ROWS / VBS)   // 512

typedef __attribute__((ext_vector_type(8))) short bf16x8s;
typedef __attribute__((ext_vector_type(4))) float f32x4;
typedef __attribute__((ext_vector_type(4))) unsigned short u16x4;
typedef __attribute__((ext_vector_type(8))) unsigned short u16x8;

static __device__ __forceinline__ short f2bf(float f) {
    unsigned u = __builtin_bit_cast(unsigned, f);
    u = u + 0x7FFFu + ((u >> 16) & 1u);   // round-to-nearest-even to bf16
    return (short)(u >> 16);
}
static __device__ __forceinline__ float bf2f(unsigned short h) {
    unsigned u = ((unsigned)h) << 16;
    return __builtin_bit_cast(float, u);
}
// packed RNE f32->bf16 pair: 1 VALU op for 2 elements
static __device__ __forceinline__ unsigned cvt_pk_bf16(float a, float b) {
    unsigned r;
    asm("v_cvt_pk_bf16_f32 %0, %1, %2" : "=v"(r) : "v"(a), "v"(b));
    return r;
}

// One block per virtual batch (chunk): 128 threads, one per feature.
__global__ void gbn_stats_kernel(const float* __restrict__ a,
                                 const float* __restrict__ gamma,
                                 const float* __restrict__ beta,
                                 float* __restrict__ ss) {
    int c = blockIdx.x;
    int j = threadIdx.x;            // feature 0..127
    const float* p = a + (size_t)c * (VBS * NA) + j;
    float s = 0.f, s2 = 0.f;
#pragma unroll 8
    for (int r = 0; r < VBS; ++r) {
        float v = p[r * NA];
        s += v; s2 += v * v;
    }
    float mean = s * (1.f / VBS);
    float var  = fmaxf(s2 * (1.f / VBS) - mean * mean, 0.f);   // biased var
    float sc = gamma[j] * rsqrtf(var + 1e-5f);
    float sh = beta[j] - mean * sc;
    float2* o = (float2*)ss + (c * NA + j);
    *o = make_float2(sc, sh);
}

// Pack W for the 4-wave kernel: chunk c = ((wv*4+ks)*16+nf)*64 + lane,
// lane=(g*16+q), holding W[wv*256 + nf*16 + q][ks*32 + g*8 .. +8].
__global__ void wpack_kernel(const float* __restrict__ W, u16x8* __restrict__ Wp) {
    int c = blockIdx.x * 256 + threadIdx.x;   // 16384 chunks
    int lane = c & 63;
    int nf   = (c >> 6) & 15;
    int ks   = (c >> 10) & 3;
    int wv   = (c >> 12) & 3;
    int g = lane >> 4, q = lane & 15;
    const float* src = W + (size_t)(wv * 256 + nf * 16 + q) * NA + ks * 32 + g * 8;
    u16x8 h;
#pragma unroll
    for (int i = 0; i < 8; ++i) h[i] = (unsigned short)f2bf(src[i]);
    Wp[c] = h;
}

// ===== real kernel: R6 structure (best known, ~175us) + cvt_pk staging =====
__global__ __launch_bounds__(256, 2) void fused_kernel(
    const float* __restrict__ a,
    const float* __restrict__ prior,
    const float* __restrict__ ss,
    const u16x8* __restrict__ Wp,
    float* __restrict__ out) {

    const int tid  = threadIdx.x;
    const int wave = tid >> 6;
    const int lane = tid & 63;
    const int g    = lane >> 4;
    const int q    = lane & 15;

    const int r0    = blockIdx.x * 16;
    const int chunk = r0 >> 7;

    float4 pr[16];
    {
        const float* pb = prior + (size_t)(r0 + q) * D_OUT + wave * 256 + 4 * g;
#pragma unroll
        for (int nf = 0; nf < 16; ++nf) pr[nf] = *(const float4*)(pb + nf * 16);
    }

    f32x4 acc[16];
#pragma unroll
    for (int i = 0; i < 16; ++i) acc[i] = (f32x4){0.f, 0.f, 0.f, 0.f};

    const float* ssb = ss + (size_t)chunk * NA * 2;

#pragma unroll
    for (int ks = 0; ks < 4; ++ks) {
        const int k0 = ks * 32 + g * 8;
        const float4* ap = (const float4*)(a + (size_t)(r0 + q) * NA + k0);
        float4 v0 = ap[0], v1 = ap[1];
        const float4* sp = (const float4*)(ssb + k0 * 2);
        float4 s0 = sp[0], s1 = sp[1], s2 = sp[2], s3 = sp[3];
        int4 ai;
        ai.x = (int)cvt_pk_bf16(v0.x * s0.x + s0.y, v0.y * s0.z + s0.w);
        ai.y = (int)cvt_pk_bf16(v0.z * s1.x + s1.y, v0.w * s1.z + s1.w);
        ai.z = (int)cvt_pk_bf16(v1.x * s2.x + s2.y, v1.y * s2.z + s2.w);
        ai.w = (int)cvt_pk_bf16(v1.z * s3.x + s3.y, v1.w * s3.z + s3.w);
        bf16x8s af = __builtin_bit_cast(bf16x8s, ai);

        const bf16x8s* wp = (const bf16x8s*)(Wp + ((size_t)(wave * 4 + ks) * 16) * 64 + lane);
#pragma unroll
        for (int nf = 0; nf < 16; ++nf) {
            bf16x8s bf = wp[nf * 64];
            acc[nf] = __builtin_amdgcn_mfma_f32_16x16x32_bf16(bf, af, acc[nf], 0, 0, 0);
        }
    }

#pragma unroll
    for (int nf = 0; nf < 16; ++nf) {
        acc[nf][0] *= pr[nf].x; acc[nf][1] *= pr[nf].y;
        acc[nf][2] *= pr[nf].z; acc[nf][3] *= pr[nf].w;
    }

    __shared__ unsigned short ls[16][1032];
#pragma unroll
    for (int nf = 0; nf < 16; ++nf) {
        uint2 hh;
        hh.x = cvt_pk_bf16(acc[nf][0], acc[nf][1]);
        hh.y = cvt_pk_bf16(acc[nf][2], acc[nf][3]);
        *(uint2*)&ls[q][wave * 256 + nf * 16 + 4 * g] = hh;
    }
    __syncthreads();

    float va[4][16];
#pragma unroll
    for (int r = 0; r < 4; ++r) {
        const int row = wave * 4 + r;
#pragma unroll
        for (int j = 0; j < 4; ++j) {
            u16x4 hv = *(const u16x4*)&ls[row][j * 256 + lane * 4];
            va[r][j * 4 + 0] = bf2f(hv[0]);
            va[r][j * 4 + 1] = bf2f(hv[1]);
            va[r][j * 4 + 2] = bf2f(hv[2]);
            va[r][j * 4 + 3] = bf2f(hv[3]);
        }
    }

    float tau[4];
    int   cp[4];
    {
        float s[4];
#pragma unroll
        for (int r = 0; r < 4; ++r) {
            float t = 0.f;
#pragma unroll
            for (int e = 0; e < 16; ++e) t += va[r][e];
            s[r] = t;
        }
#pragma unroll
        for (int m = 1; m < 64; m <<= 1) {
#pragma unroll
            for (int r = 0; r < 4; ++r) s[r] += __shfl_xor(s[r], m);
        }
#pragma unroll
        for (int r = 0; r < 4; ++r) {
            tau[r] = (s[r] - 1.f) * (1.f / 1024.f);
            cp[r]  = 1024;
        }
    }

#pragma unroll 1
    for (int it = 0; it < 32; ++it) {
        float S[4];
        int   C[4];
#pragma unroll
        for (int r = 0; r < 4; ++r) {
            float s1 = 0.f;
            int   c  = 0;
#pragma unroll
            for (int e = 0; e < 16; ++e) {
                float d = va[r][e] - tau[r];
                s1 += fmaxf(d, 0.f);
                c  += (int)__popcll(__ballot(d > 0.f));
            }
            S[r] = s1; C[r] = c;
        }
#pragma unroll
        for (int m = 1; m < 64; m <<= 1) {
#pragma unroll
            for (int r = 0; r < 4; ++r) S[r] += __shfl_xor(S[r], m);
        }
        bool all_done = true;
#pragma unroll
        for (int r = 0; r < 4; ++r) {
            tau[r] += (S[r] - 1.f) * __builtin_amdgcn_rcpf((float)C[r]);
            all_done = all_done && (C[r] == cp[r]);
            cp[r] = C[r];
        }
        if (all_done) break;
    }

#pragma unroll
    for (int r = 0; r < 4; ++r) {
        const int row = wave * 4 + r;
        float* ob = out + (size_t)(r0 + row) * D_OUT + lane * 4;
#pragma unroll
        for (int j = 0; j < 4; ++j) {
            float4 o;
            o.x = fmaxf(va[r][j * 4 + 0] + tau[r], 0.f);
            o.y = fmaxf(va[r][j * 4 + 1] + tau[r], 0.f);
            o.z = fmaxf(va[r][j * 4 + 2] + tau[r], 0.f);
            o.w = fmaxf(va[r][j * 4 + 3] + tau[r], 0.f);
            *(float4*)(ob + j * 256) = o;
        }
    }
}

// ===== ablation: GEMM phase (WITH_PRIOR: + 256MB prior stream + multiply) =====
template<int WITH_PRIOR>
__global__ __launch_bounds__(256, 2) void abl_gemm(
    const float* __restrict__ a,
    const float* __restrict__ prior,
    const float* __restrict__ ss,
    const u16x8* __restrict__ Wp,
    float4* __restrict__ wsout) {

    const int tid  = threadIdx.x;
    const int wave = tid >> 6;
    const int lane = tid & 63;
    const int g    = lane >> 4;
    const int q    = lane & 15;
    const int r0    = blockIdx.x * 16;
    const int chunk = r0 >> 7;

    float4 pr[16];
    if (WITH_PRIOR) {
        const float* pb = prior + (size_t)(r0 + q) * D_OUT + wave * 256 + 4 * g;
#pragma unroll
        for (int nf = 0; nf < 16; ++nf) pr[nf] = *(const float4*)(pb + nf * 16);
    }

    f32x4 acc[16];
#pragma unroll
    for (int i = 0; i < 16; ++i) acc[i] = (f32x4){0.f, 0.f, 0.f, 0.f};

    const float* ssb = ss + (size_t)chunk * NA * 2;

#pragma unroll
    for (int ks = 0; ks < 4; ++ks) {
        const int k0 = ks * 32 + g * 8;
        const float4* ap = (const float4*)(a + (size_t)(r0 + q) * NA + k0);
        float4 v0 = ap[0], v1 = ap[1];
        const float4* sp = (const float4*)(ssb + k0 * 2);
        float4 s0 = sp[0], s1 = sp[1], s2 = sp[2], s3 = sp[3];
        int4 ai;
        ai.x = (int)cvt_pk_bf16(v0.x * s0.x + s0.y, v0.y * s0.z + s0.w);
        ai.y = (int)cvt_pk_bf16(v0.z * s1.x + s1.y, v0.w * s1.z + s1.w);
        ai.z = (int)cvt_pk_bf16(v1.x * s2.x + s2.y, v1.y * s2.z + s2.w);
        ai.w = (int)cvt_pk_bf16(v1.z * s3.x + s3.y, v1.w * s3.z + s3.w);
        bf16x8s af = __builtin_bit_cast(bf16x8s, ai);

        const bf16x8s* wp = (const bf16x8s*)(Wp + ((size_t)(wave * 4 + ks) * 16) * 64 + lane);
#pragma unroll
        for (int nf = 0; nf < 16; ++nf) {
            bf16x8s bf = wp[nf * 64];
            acc[nf] = __builtin_amdgcn_mfma_f32_16x16x32_bf16(bf, af, acc[nf], 0, 0, 0);
        }
    }

    if (WITH_PRIOR) {
#pragma unroll
        for (int nf = 0; nf < 16; ++nf) {
            acc[nf][0] *= pr[nf].x; acc[nf][1] *= pr[nf].y;
            acc[nf][2] *= pr[nf].z; acc[nf][3] *= pr[nf].w;
        }
    }

    // keep every acc live; 16 B/thread store (negligible traffic)
    f32x4 r = acc[0];
#pragma unroll
    for (int nf = 1; nf < 16; ++nf) {
        r[0] += acc[nf][0]; r[1] += acc[nf][1];
        r[2] += acc[nf][2]; r[3] += acc[nf][3];
    }
    float4 o; o.x = r[0]; o.y = r[1]; o.z = r[2]; o.w = r[3];
    wsout[(size_t)blockIdx.x * 256 + tid] = o;
}

// ===== ablation: epilogue phase (prior-fed acc -> transpose -> Michelot) =====
__global__ __launch_bounds__(256, 2) void abl_epi(
    const float* __restrict__ prior,
    float* __restrict__ wsout) {

    const int tid  = threadIdx.x;
    const int wave = tid >> 6;
    const int lane = tid & 63;
    const int g    = lane >> 4;
    const int q    = lane & 15;
    const int r0   = blockIdx.x * 16;

    float4 pr[16];
    {
        const float* pb = prior + (size_t)(r0 + q) * D_OUT + wave * 256 + 4 * g;
#pragma unroll
        for (int nf = 0; nf < 16; ++nf) pr[nf] = *(const float4*)(pb + nf * 16);
    }

    __shared__ unsigned short ls[16][1032];
#pragma unroll
    for (int nf = 0; nf < 16; ++nf) {
        uint2 hh;
        hh.x = cvt_pk_bf16(pr[nf].x, pr[nf].y);
        hh.y = cvt_pk_bf16(pr[nf].z, pr[nf].w);
        *(uint2*)&ls[q][wave * 256 + nf * 16 + 4 * g] = hh;
    }
    __syncthreads();

    float va[4][16];
#pragma unroll
    for (int r = 0; r < 4; ++r) {
        const int row = wave * 4 + r;
#pragma unroll
        for (int j = 0; j < 4; ++j) {
            u16x4 hv = *(const u16x4*)&ls[row][j * 256 + lane * 4];
            va[r][j * 4 + 0] = bf2f(hv[0]);
            va[r][j * 4 + 1] = bf2f(hv[1]);
            va[r][j * 4 + 2] = bf2f(hv[2]);
            va[r][j * 4 + 3] = bf2f(hv[3]);
        }
    }

    float tau[4];
    int   cp[4];
    {
        float s[4];
#pragma unroll
        for (int r = 0; r < 4; ++r) {
            float t = 0.f;
#pragma unroll
            for (int e = 0; e < 16; ++e) t += va[r][e];
            s[r] = t;
        }
#pragma unroll
        for (int m = 1; m < 64; m <<= 1) {
#pragma unroll
            for (int r = 0; r < 4; ++r) s[r] += __shfl_xor(s[r], m);
        }
#pragma unroll
        for (int r = 0; r < 4; ++r) {
            tau[r] = (s[r] - 1.f) * (1.f / 1024.f);
            cp[r]  = 1024;
        }
    }

#pragma unroll 1
    for (int it = 0; it < 32; ++it) {
        float S[4];
        int   C[4];
#pragma unroll
        for (int r = 0; r < 4; ++r) {
            float s1 = 0.f;
            int   c  = 0;
#pragma unroll
            for (int e = 0; e < 16; ++e) {
                float d = va[r][e] - tau[r];
                s1 += fmaxf(d, 0.f);
                c  += (int)__popcll(__ballot(d > 0.f));
            }
            S[r] = s1; C[r] = c;
        }
#pragma unroll
        for (int m = 1; m < 64; m <<= 1) {
#pragma unroll
            for (int r = 0; r < 4; ++r) S[r] += __shfl_xor(S[r], m);
        }
        bool all_done = true;
#pragma unroll
        for (int r = 0; r < 4; ++r) {
            tau[r] += (S[r] - 1.f) * __builtin_amdgcn_rcpf((float)C[r]);
            all_done = all_done && (C[r] == cp[r]);
            cp[r] = C[r];
        }
        if (all_done) break;
    }

    float o = 0.f;
#pragma unroll
    for (int r = 0; r < 4; ++r)
#pragma unroll
        for (int e = 0; e < 16; ++e) o += fmaxf(va[r][e] + tau[r], 0.f);
    wsout[(size_t)blockIdx.x * 256 + tid] = o;
}

extern "C" void kernel_launch(void* const* d_in, const int* in_sizes, int n_in,
                              void* d_out, int out_size, void* d_ws, size_t ws_size,
                              hipStream_t stream) {
    const float* a     = (const float*)d_in[0];
    const float* prior = (const float*)d_in[1];
    const float* gamma = (const float*)d_in[2];
    const float* beta  = (const float*)d_in[3];
    const float* W     = (const float*)d_in[4];
    float* out = (float*)d_out;

    float* ss = (float*)d_ws;                              // 512 KB @ 0
    u16x8* Wp = (u16x8*)((char*)d_ws + 524288);            // 256 KB @ 512K
    float4* wsg1 = (float4*)((char*)d_ws + (1u << 20));    // 16 MB @ 1M
    float4* wsg2 = (float4*)((char*)d_ws + (32u << 20));   // 16 MB @ 32M
    float*  wse  = (float*)((char*)d_ws + (64u << 20));    //  4 MB @ 64M

    gbn_stats_kernel<<<NCHUNK, VBS, 0, stream>>>(a, gamma, beta, ss);
    wpack_kernel<<<64, 256, 0, stream>>>(W, Wp);
    fused_kernel<<<B_ROWS / 16, 256, 0, stream>>>(a, prior, ss, Wp, out);

    const bool do_abl = ws_size >= (80u << 20);
    if (do_abl) {
        abl_gemm<0><<<B_ROWS / 16, 256, 0, stream>>>(a, prior, ss, Wp, wsg2);
        abl_gemm<1><<<B_ROWS / 16, 256, 0, stream>>>(a, prior, ss, Wp, wsg1);
        abl_epi<<<B_ROWS / 16, 256, 0, stream>>>(prior, wse);
    }
}

// Round 13
// 168.411 us; speedup vs baseline: 2.5210x; 2.5210x over previous
//
#include <hip/hip_runtime.h>
#include <hip/hip_bf16.h>

#define B_ROWS 65536
#define NA 128
#define D_OUT 1024
#define VBS 128
#define NCHUNK (B_ROWS / VBS)   // 512

typedef __attribute__((ext_vector_type(8))) short bf16x8s;
typedef __attribute__((ext_vector_type(4))) float f32x4;
typedef __attribute__((ext_vector_type(2))) float f32x2;
typedef __attribute__((ext_vector_type(4))) unsigned short u16x4;
typedef __attribute__((ext_vector_type(8))) unsigned short u16x8;

static __device__ __forceinline__ short f2bf(float f) {
    unsigned u = __builtin_bit_cast(unsigned, f);
    u = u + 0x7FFFu + ((u >> 16) & 1u);   // round-to-nearest-even to bf16
    return (short)(u >> 16);
}
static __device__ __forceinline__ float bf2f(unsigned short h) {
    unsigned u = ((unsigned)h) << 16;
    return __builtin_bit_cast(float, u);
}
// packed RNE f32->bf16 pair: 1 VALU op for 2 elements
static __device__ __forceinline__ unsigned cvt_pk_bf16(float a, float b) {
    unsigned r;
    asm("v_cvt_pk_bf16_f32 %0, %1, %2" : "=v"(r) : "v"(a), "v"(b));
    return r;
}

// One block per chunk: compute GBN stats, then write normalized a as bf16.
// Second read of the 64KB chunk hits L2. Removes ALL staging VALU from fused.
__global__ void gbn_norm_kernel(const float* __restrict__ a,
                                const float* __restrict__ gamma,
                                const float* __restrict__ beta,
                                unsigned short* __restrict__ ab) {
    int c = blockIdx.x;
    int j = threadIdx.x;            // feature 0..127
    const float* p = a + (size_t)c * (VBS * NA) + j;
    float s = 0.f, s2 = 0.f;
#pragma unroll 8
    for (int r = 0; r < VBS; ++r) {
        float v = p[r * NA];
        s += v; s2 += v * v;
    }
    float mean = s * (1.f / VBS);
    float var  = fmaxf(s2 * (1.f / VBS) - mean * mean, 0.f);   // biased var
    float sc = gamma[j] * rsqrtf(var + 1e-5f);
    float sh = beta[j] - mean * sc;
    unsigned short* o = ab + (size_t)c * (VBS * NA) + j;
#pragma unroll 8
    for (int r = 0; r < VBS; ++r) {
        float v = p[r * NA];
        o[r * NA] = (unsigned short)f2bf(v * sc + sh);
    }
}

// Pack W: chunk c = ((wv*4+ks)*16+nf)*64 + lane, lane=(g*16+q),
// holding W[wv*256 + nf*16 + q][ks*32 + g*8 .. +8].
__global__ void wpack_kernel(const float* __restrict__ W, u16x8* __restrict__ Wp) {
    int c = blockIdx.x * 256 + threadIdx.x;   // 16384 chunks
    int lane = c & 63;
    int nf   = (c >> 6) & 15;
    int ks   = (c >> 10) & 3;
    int wv   = (c >> 12) & 3;
    int g = lane >> 4, q = lane & 15;
    const float* src = W + (size_t)(wv * 256 + nf * 16 + q) * NA + ks * 32 + g * 8;
    u16x8 h;
#pragma unroll
    for (int i = 0; i < 8; ++i) h[i] = (unsigned short)f2bf(src[i]);
    Wp[c] = h;
}

// One block per 16 rows; wave w owns cols [w*256,+256). Swapped-operand MFMA.
// Epilogue: *prior (registers), bf16 LDS transpose, then 4-row-interleaved
// WARM-STARTED Michelot (tau0 = rowmax-1, a provable lower bracket) with
// packed-pair (f32x2 -> v_pk_*) scans; count via ballot+popc on SALU.
__global__ __launch_bounds__(256, 2) void fused_kernel(
    const unsigned short* __restrict__ ab,
    const float* __restrict__ prior,
    const u16x8* __restrict__ Wp,
    float* __restrict__ out) {

    const int tid  = threadIdx.x;
    const int wave = tid >> 6;        // 0..3  (N block of 256)
    const int lane = tid & 63;
    const int g    = lane >> 4;       // 0..3
    const int q    = lane & 15;       // output row within tile

    const int r0 = blockIdx.x * 16;

    // ---- prefetch prior into registers (HBM latency overlaps GEMM) ----
    float4 pr[16];
    {
        const float* pb = prior + (size_t)(r0 + q) * D_OUT + wave * 256 + 4 * g;
#pragma unroll
        for (int nf = 0; nf < 16; ++nf) pr[nf] = *(const float4*)(pb + nf * 16);
    }

    f32x4 acc[16];
#pragma unroll
    for (int i = 0; i < 16; ++i) acc[i] = (f32x4){0.f, 0.f, 0.f, 0.f};

    // ---- GEMM: y = GBN(a)[16x128] * W^T; A-fragments load directly as bf16 ----
#pragma unroll
    for (int ks = 0; ks < 4; ++ks) {
        const int k0 = ks * 32 + g * 8;
        bf16x8s af = *(const bf16x8s*)(ab + (size_t)(r0 + q) * NA + k0);

        const bf16x8s* wp = (const bf16x8s*)(Wp + ((size_t)(wave * 4 + ks) * 16) * 64 + lane);
#pragma unroll
        for (int nf = 0; nf < 16; ++nf) {
            bf16x8s bf = wp[nf * 64];
            acc[nf] = __builtin_amdgcn_mfma_f32_16x16x32_bf16(bf, af, acc[nf], 0, 0, 0);
        }
    }

    // ---- multiply by prior (from registers) ----
#pragma unroll
    for (int nf = 0; nf < 16; ++nf) {
        acc[nf][0] *= pr[nf].x; acc[nf][1] *= pr[nf].y;
        acc[nf][2] *= pr[nf].z; acc[nf][3] *= pr[nf].w;
    }

    // ---- transpose through LDS (bf16, padded layout) ----
    __shared__ unsigned short ls[16][1032];   // 1032 = 1024 + 8 pad, 33 KB
#pragma unroll
    for (int nf = 0; nf < 16; ++nf) {
        uint2 hh;
        hh.x = cvt_pk_bf16(acc[nf][0], acc[nf][1]);
        hh.y = cvt_pk_bf16(acc[nf][2], acc[nf][3]);
        *(uint2*)&ls[q][wave * 256 + nf * 16 + 4 * g] = hh;
    }
    __syncthreads();

    // ---- load this wave's 4 rows as f32x2 pairs: va[4][8] ----
    f32x2 va[4][8];
#pragma unroll
    for (int r = 0; r < 4; ++r) {
        const int row = wave * 4 + r;
#pragma unroll
        for (int j = 0; j < 4; ++j) {
            u16x4 hv = *(const u16x4*)&ls[row][j * 256 + lane * 4];
            va[r][2 * j + 0] = (f32x2){bf2f(hv[0]), bf2f(hv[1])};
            va[r][2 * j + 1] = (f32x2){bf2f(hv[2]), bf2f(hv[3])};
        }
    }

    // ---- row maxima (packed tree + wave reduce) -> tau0 = max - 1 ----
    float mx[4];
#pragma unroll
    for (int r = 0; r < 4; ++r) {
        f32x2 m2 = va[r][0];
#pragma unroll
        for (int e = 1; e < 8; ++e) m2 = __builtin_elementwise_max(m2, va[r][e]);
        mx[r] = fmaxf(m2[0], m2[1]);
    }
#pragma unroll
    for (int m = 1; m < 64; m <<= 1) {
#pragma unroll
        for (int r = 0; r < 4; ++r) mx[r] = fmaxf(mx[r], __shfl_xor(mx[r], m));
    }

    float tau[4];
    int   cp[4];
#pragma unroll
    for (int r = 0; r < 4; ++r) { tau[r] = mx[r] - 1.f; cp[r] = -1; }

    // ---- Michelot from the bracket: tau += (F(tau)-1)/C, monotone up ----
#pragma unroll 1
    for (int it = 0; it < 16; ++it) {
        f32x2 t2[4];
#pragma unroll
        for (int r = 0; r < 4; ++r) t2[r] = (f32x2){tau[r], tau[r]};
        f32x2 S2[4];
        int   C[4];
#pragma unroll
        for (int r = 0; r < 4; ++r) { S2[r] = (f32x2){0.f, 0.f}; C[r] = 0; }
#pragma unroll
        for (int e = 0; e < 8; ++e) {
#pragma unroll
            for (int r = 0; r < 4; ++r) {
                f32x2 d = va[r][e] - t2[r];
                S2[r] += __builtin_elementwise_max(d, (f32x2){0.f, 0.f});
                C[r] += (int)__popcll(__ballot(d[0] > 0.f));
                C[r] += (int)__popcll(__ballot(d[1] > 0.f));
            }
        }
        float S[4];
#pragma unroll
        for (int r = 0; r < 4; ++r) S[r] = S2[r][0] + S2[r][1];
#pragma unroll
        for (int m = 1; m < 64; m <<= 1) {
#pragma unroll
            for (int r = 0; r < 4; ++r) S[r] += __shfl_xor(S[r], m);
        }
        bool all_done = true;
#pragma unroll
        for (int r = 0; r < 4; ++r) {
            tau[r] += (S[r] - 1.f) * __builtin_amdgcn_rcpf((float)C[r]);
            all_done = all_done && (C[r] == cp[r]);
            cp[r] = C[r];
        }
        if (all_done) break;
    }

    // ---- output: reference computes relu(x + tau_std) -> ADD tau (R6/R9-validated) ----
#pragma unroll
    for (int r = 0; r < 4; ++r) {
        const int row = wave * 4 + r;
        f32x2 t2 = (f32x2){tau[r], tau[r]};
        float* ob = out + (size_t)(r0 + row) * D_OUT + lane * 4;
#pragma unroll
        for (int j = 0; j < 4; ++j) {
            f32x2 o0 = __builtin_elementwise_max(va[r][2 * j + 0] + t2, (f32x2){0.f, 0.f});
            f32x2 o1 = __builtin_elementwise_max(va[r][2 * j + 1] + t2, (f32x2){0.f, 0.f});
            float4 o;
            o.x = o0[0]; o.y = o0[1]; o.z = o1[0]; o.w = o1[1];
            *(float4*)(ob + j * 256) = o;
        }
    }
}

extern "C" void kernel_launch(void* const* d_in, const int* in_sizes, int n_in,
                              void* d_out, int out_size, void* d_ws, size_t ws_size,
                              hipStream_t stream) {
    const float* a     = (const float*)d_in[0];
    const float* prior = (const float*)d_in[1];
    const float* gamma = (const float*)d_in[2];
    const float* beta  = (const float*)d_in[3];
    const float* W     = (const float*)d_in[4];
    float* out = (float*)d_out;

    u16x8*          Wp = (u16x8*)d_ws;                           // 256 KB @ 0
    unsigned short* ab = (unsigned short*)((char*)d_ws + 262144); // 16 MB @ 256K

    gbn_norm_kernel<<<NCHUNK, VBS, 0, stream>>>(a, gamma, beta, ab);
    wpack_kernel<<<64, 256, 0, stream>>>(W, Wp);
    fused_kernel<<<B_ROWS / 16, 256, 0, stream>>>(ab, prior, Wp, out);
}